// Round 4
// baseline (395.290 us; speedup 1.0000x reference)
//
#include <hip/hip_runtime.h>

#define B 4
#define C 19
#define H 192
#define W 192
// 40 / ln(2): exp(-40*x) == exp2(-THETA_LOG2E*x)
#define THETA_LOG2E 57.70780163555855f

#define NT 768      // threads per block (12 waves)
#define SEGS 8      // segments per scan line
#define SR 24       // elements per segment (192/8)
#define CH 96       // lines per chunk (2 chunks cover 192 lines)
#define PITCH 193   // LDS plane pitch (+1 pad: row-direction reads stride 193 -> conflict-free)

// ---------------- setup: dmat = exp2(-theta*relu(edge)), plus transposed copy ----------------
__global__ __launch_bounds__(256) void k_prep(const float* __restrict__ edge,
                                              float* __restrict__ dmat,
                                              float* __restrict__ dmatT) {
    __shared__ float tile[32][33];
    int blk = blockIdx.x;                 // b*36 + ty*6 + tx
    int tx = blk % 6, ty = (blk / 6) % 6, b = blk / 36;
    int lx = threadIdx.x % 32, ly = threadIdx.x / 32;    // 32 x 8
    #pragma unroll
    for (int k = 0; k < 4; ++k) {
        int il = ly + k * 8;
        int I = ty * 32 + il, J = tx * 32 + lx;
        float e = edge[(b * H + I) * W + J];
        float d = exp2f(-THETA_LOG2E * fmaxf(e, 0.f));
        dmat[(b * H + I) * W + J] = d;
        tile[il][lx] = d;
    }
    __syncthreads();
    #pragma unroll
    for (int k = 0; k < 4; ++k) {
        int jl = ly + k * 8;
        // dmatT[b][J][I] = d(I,J); lanes vary I -> coalesced
        dmatT[(b * W + tx * 32 + jl) * H + ty * 32 + lx] = tile[lx][jl];
    }
}

// segment-compose: inclusive prefix (fwd, threads 0..95) / inclusive suffix (bwd, threads 96..191)
// over the 8 per-segment affine transforms (P, Q):  Z_out = P*Z_in + Q
__device__ __forceinline__ void compose_scr(float2* sF, float2* sB, int t) {
    if (t < CH) {
        float P = sF[t].x, Q = sF[t].y;
        #pragma unroll
        for (int s = 1; s < SEGS; ++s) {
            float2 v = sF[s * CH + t];
            Q = Q * v.x + v.y;
            P = P * v.x;
            sF[s * CH + t] = make_float2(P, Q);
        }
    } else if (t < 2 * CH) {
        const int x = t - CH;
        float P = sB[(SEGS - 1) * CH + x].x, Q = sB[(SEGS - 1) * CH + x].y;
        #pragma unroll
        for (int s = SEGS - 2; s >= 0; --s) {
            float2 v = sB[s * CH + x];
            Q = Q * v.x + v.y;
            P = P * v.x;
            sB[s * CH + x] = make_float2(P, Q);
        }
    }
}

// ---------------- fused: denominator + all 3 iterations for one (b,c) plane ----------------
__global__ __launch_bounds__(NT) void k_fused(const float* __restrict__ mask,
                                              const float* __restrict__ dmatg,
                                              const float* __restrict__ dmatTg,
                                              float* __restrict__ outg) {
    __shared__ float plane[H * PITCH];       // 148224 B
    __shared__ float2 scrF[SEGS * CH];       // 6144 B
    __shared__ float2 scrB[SEGS * CH];       // 6144 B  (total 160512 <= 163840)

    const int t = threadIdx.x;
    const int lc = t % CH;        // line index within chunk
    const int seg = t / CH;       // 0..7
    const int r0 = seg * SR;

    const int b = blockIdx.x / C;
    const int c = blockIdx.x % C;
    const float* dm  = dmatg  + b * H * W;
    const float* dmT = dmatTg + b * H * W;

    float rD[2 * SR];             // 1/D at col-ownership (i=r0+r, j=chunk*CH+lc)
    float cs[2 * SR];             // col-scan result, same ownership

    // ===== setup phase A: row-direction unit scans -> plane[i][s] = Zr + Sr - 2 =====
    #pragma unroll
    for (int chunk = 0; chunk < 2; ++chunk) {
        const int i = chunk * CH + lc;
        float dr[SR + 1];
        #pragma unroll
        for (int r = 0; r < SR; ++r) dr[r] = dmT[(r0 + r) * H + i];
        dr[SR] = (seg < SEGS - 1) ? dmT[(r0 + SR) * H + i] : 0.f;
        float Pf = 1.f, Qf = 0.f, Pb = 1.f, Qb = 0.f;
        #pragma unroll
        for (int r = 0; r < SR; ++r) { Qf = Qf * dr[r] + 1.f; Pf *= dr[r]; }
        #pragma unroll
        for (int r = SR - 1; r >= 0; --r) { Qb = Qb * dr[r + 1] + 1.f; Pb *= dr[r + 1]; }
        scrF[seg * CH + lc] = make_float2(Pf, Qf);
        scrB[seg * CH + lc] = make_float2(Pb, Qb);
        __syncthreads();
        compose_scr(scrF, scrB, t);
        __syncthreads();
        float z = (seg > 0) ? scrF[(seg - 1) * CH + lc].y : 0.f;
        float s = (seg < SEGS - 1) ? scrB[(seg + 1) * CH + lc].y : 0.f;
        float zarr[SR];
        #pragma unroll
        for (int r = 0; r < SR; ++r) { z = z * dr[r] + 1.f; zarr[r] = z; }
        #pragma unroll
        for (int r = SR - 1; r >= 0; --r) {
            s = s * dr[r + 1] + 1.f;
            plane[i * PITCH + r0 + r] = zarr[r] + s - 2.f;
        }
        __syncthreads();
    }

    // ===== setup phase B: col-direction unit scans -> rD = 1/(Zc+Sc-1 + rowDpart) =====
    #pragma unroll
    for (int chunk = 0; chunk < 2; ++chunk) {
        const int j = chunk * CH + lc;
        float dr[SR + 1];
        #pragma unroll
        for (int r = 0; r < SR; ++r) dr[r] = dm[(r0 + r) * W + j];
        dr[SR] = (seg < SEGS - 1) ? dm[(r0 + SR) * W + j] : 0.f;
        float Pf = 1.f, Qf = 0.f, Pb = 1.f, Qb = 0.f;
        #pragma unroll
        for (int r = 0; r < SR; ++r) { Qf = Qf * dr[r] + 1.f; Pf *= dr[r]; }
        #pragma unroll
        for (int r = SR - 1; r >= 0; --r) { Qb = Qb * dr[r + 1] + 1.f; Pb *= dr[r + 1]; }
        scrF[seg * CH + lc] = make_float2(Pf, Qf);
        scrB[seg * CH + lc] = make_float2(Pb, Qb);
        __syncthreads();
        compose_scr(scrF, scrB, t);
        __syncthreads();
        float z = (seg > 0) ? scrF[(seg - 1) * CH + lc].y : 0.f;
        float s = (seg < SEGS - 1) ? scrB[(seg + 1) * CH + lc].y : 0.f;
        float zarr[SR];
        #pragma unroll
        for (int r = 0; r < SR; ++r) { z = z * dr[r] + 1.f; zarr[r] = z; }
        #pragma unroll
        for (int r = SR - 1; r >= 0; --r) {
            s = s * dr[r + 1] + 1.f;
            rD[chunk * SR + r] = 1.f / (zarr[r] + s - 1.f + plane[(r0 + r) * PITCH + j]);
        }
        __syncthreads();
    }

    // ===== load f = mask plane into LDS =====
    const float* fin = mask + (size_t)(b * C + c) * H * W;
    #pragma unroll
    for (int k = 0; k < (H * W / 4) / NT; ++k) {     // 12
        int e4 = t + k * NT;
        float4 v = ((const float4*)fin)[e4];
        int i = e4 / 48;              // 48 float4 per row
        int j4 = (e4 % 48) * 4;
        plane[i * PITCH + j4 + 0] = v.x;
        plane[i * PITCH + j4 + 1] = v.y;
        plane[i * PITCH + j4 + 2] = v.z;
        plane[i * PITCH + j4 + 3] = v.w;
    }
    __syncthreads();

    // ===== 3 iterations, fully in LDS =====
    for (int it = 0; it < 3; ++it) {
        // ---- col scans: cs = Zc + Sc - f (reads plane, results in regs) ----
        #pragma unroll
        for (int chunk = 0; chunk < 2; ++chunk) {
            const int j = chunk * CH + lc;
            float dr[SR + 1], fr[SR];
            #pragma unroll
            for (int r = 0; r < SR; ++r) {
                dr[r] = dm[(r0 + r) * W + j];
                fr[r] = plane[(r0 + r) * PITCH + j];
            }
            dr[SR] = (seg < SEGS - 1) ? dm[(r0 + SR) * W + j] : 0.f;
            float Pf = 1.f, Qf = 0.f, Pb = 1.f, Qb = 0.f;
            #pragma unroll
            for (int r = 0; r < SR; ++r) { Qf = Qf * dr[r] + fr[r]; Pf *= dr[r]; }
            #pragma unroll
            for (int r = SR - 1; r >= 0; --r) { Qb = Qb * dr[r + 1] + fr[r]; Pb *= dr[r + 1]; }
            scrF[seg * CH + lc] = make_float2(Pf, Qf);
            scrB[seg * CH + lc] = make_float2(Pb, Qb);
            __syncthreads();
            compose_scr(scrF, scrB, t);
            __syncthreads();
            float z = (seg > 0) ? scrF[(seg - 1) * CH + lc].y : 0.f;
            float s = (seg < SEGS - 1) ? scrB[(seg + 1) * CH + lc].y : 0.f;
            #pragma unroll
            for (int r = 0; r < SR; ++r) { z = z * dr[r] + fr[r]; cs[chunk * SR + r] = z; }
            #pragma unroll
            for (int r = SR - 1; r >= 0; --r) {
                s = s * dr[r + 1] + fr[r];
                cs[chunk * SR + r] += s - fr[r];
            }
            __syncthreads();
        }
        // ---- row scans: rowpart = Zr + Sr - 2f, written over plane (row ownership) ----
        #pragma unroll
        for (int chunk = 0; chunk < 2; ++chunk) {
            const int i = chunk * CH + lc;
            float dr[SR + 1], fr[SR];
            #pragma unroll
            for (int r = 0; r < SR; ++r) {
                dr[r] = dmT[(r0 + r) * H + i];
                fr[r] = plane[i * PITCH + r0 + r];
            }
            dr[SR] = (seg < SEGS - 1) ? dmT[(r0 + SR) * H + i] : 0.f;
            float Pf = 1.f, Qf = 0.f, Pb = 1.f, Qb = 0.f;
            #pragma unroll
            for (int r = 0; r < SR; ++r) { Qf = Qf * dr[r] + fr[r]; Pf *= dr[r]; }
            #pragma unroll
            for (int r = SR - 1; r >= 0; --r) { Qb = Qb * dr[r + 1] + fr[r]; Pb *= dr[r + 1]; }
            scrF[seg * CH + lc] = make_float2(Pf, Qf);
            scrB[seg * CH + lc] = make_float2(Pb, Qb);
            __syncthreads();
            compose_scr(scrF, scrB, t);
            __syncthreads();
            float z = (seg > 0) ? scrF[(seg - 1) * CH + lc].y : 0.f;
            float s = (seg < SEGS - 1) ? scrB[(seg + 1) * CH + lc].y : 0.f;
            float zarr[SR];
            #pragma unroll
            for (int r = 0; r < SR; ++r) { z = z * dr[r] + fr[r]; zarr[r] = z; }
            #pragma unroll
            for (int r = SR - 1; r >= 0; --r) {
                s = s * dr[r + 1] + fr[r];
                plane[i * PITCH + r0 + r] = zarr[r] + s - 2.f * fr[r];
            }
            __syncthreads();
        }
        // ---- combine (col ownership): f_next = (cs + rowpart) * rD ----
        #pragma unroll
        for (int chunk = 0; chunk < 2; ++chunk) {
            const int j = chunk * CH + lc;
            #pragma unroll
            for (int r = 0; r < SR; ++r) {
                const int a = (r0 + r) * PITCH + j;
                plane[a] = (cs[chunk * SR + r] + plane[a]) * rD[chunk * SR + r];
            }
        }
        __syncthreads();
    }

    // ===== store final plane =====
    float* oplane = outg + (size_t)(b * C + c) * H * W;
    #pragma unroll
    for (int k = 0; k < (H * W / 4) / NT; ++k) {
        int e4 = t + k * NT;
        int i = e4 / 48;
        int j4 = (e4 % 48) * 4;
        float4 v;
        v.x = plane[i * PITCH + j4 + 0];
        v.y = plane[i * PITCH + j4 + 1];
        v.z = plane[i * PITCH + j4 + 2];
        v.w = plane[i * PITCH + j4 + 3];
        ((float4*)oplane)[e4] = v;
    }
}

extern "C" void kernel_launch(void* const* d_in, const int* in_sizes, int n_in,
                              void* d_out, int out_size, void* d_ws, size_t ws_size,
                              hipStream_t stream) {
    const float* mask = (const float*)d_in[0];
    const float* edge = (const float*)d_in[1];
    float* out = (float*)d_out;

    float* dmat  = (float*)d_ws;            // [B,H,W]
    float* dmatT = dmat + B * H * W;        // [B,W,H]

    k_prep<<<B * 36, 256, 0, stream>>>(edge, dmat, dmatT);
    k_fused<<<B * C, NT, 0, stream>>>(mask, dmat, dmatT, out);
}

// Round 5
// 341.169 us; speedup vs baseline: 1.1586x; 1.1586x over previous
//
#include <hip/hip_runtime.h>

#define B 4
#define C 19
#define H 192
#define W 192
// 40 / ln(2): exp(-40*x) == exp2(-THETA_LOG2E*x)
#define THETA_LOG2E 57.70780163555855f

#define NT 768      // threads per block (12 waves); 160KB LDS -> 1 block/CU -> 3 waves/SIMD
#define SEGS 8      // segments per scan line
#define SR 24       // elements per segment (192/8)
#define CH 96       // lines per chunk (2 chunks cover 192 lines)
#define PITCH 193   // LDS plane pitch (+1: both row- and col-direction accesses conflict-free)

// ---------------- setup: dmat = exp2(-theta*relu(edge)), plus transposed copy ----------------
__global__ __launch_bounds__(256) void k_prep(const float* __restrict__ edge,
                                              float* __restrict__ dmat,
                                              float* __restrict__ dmatT) {
    __shared__ float tile[32][33];
    int blk = blockIdx.x;                 // b*36 + ty*6 + tx
    int tx = blk % 6, ty = (blk / 6) % 6, b = blk / 36;
    int lx = threadIdx.x % 32, ly = threadIdx.x / 32;    // 32 x 8
    #pragma unroll
    for (int k = 0; k < 4; ++k) {
        int il = ly + k * 8;
        int I = ty * 32 + il, J = tx * 32 + lx;
        float e = edge[(b * H + I) * W + J];
        float d = exp2f(-THETA_LOG2E * fmaxf(e, 0.f));
        dmat[(b * H + I) * W + J] = d;
        tile[il][lx] = d;
    }
    __syncthreads();
    #pragma unroll
    for (int k = 0; k < 4; ++k) {
        int jl = ly + k * 8;
        dmatT[(b * W + tx * 32 + jl) * H + ty * 32 + lx] = tile[lx][jl];
    }
}

// ---------------- setup: dcol[b,i,j] = Zc + Sc - 1 (unit-f column scan) ----------------
__global__ __launch_bounds__(512) void k_dcol(const float* __restrict__ dmat,
                                              float* __restrict__ dcol) {
    int blk = blockIdx.x;                 // b*3 + jt
    int jt = blk % 3, b = blk / 3;
    int jl = threadIdx.x & 63;
    int seg = threadIdx.x >> 6;
    int j = jl + jt * 64;
    int i0 = seg * SR;
    const float* dp = dmat + ((size_t)b * H + i0) * W + j;
    float* op = dcol + ((size_t)b * H + i0) * W + j;

    float dr[SR + 1];
    #pragma unroll
    for (int r = 0; r < SR; ++r) dr[r] = dp[r * W];
    dr[SR] = (seg < SEGS - 1) ? dp[SR * W] : 0.f;
    float Pf = 1.f, Qf = 0.f, Pb = 1.f, Qb = 0.f;
    #pragma unroll
    for (int r = 0; r < SR; ++r) { Qf = Qf * dr[r] + 1.f; Pf *= dr[r]; }
    #pragma unroll
    for (int r = SR - 1; r >= 0; --r) { Qb = Qb * dr[r + 1] + 1.f; Pb *= dr[r + 1]; }

    __shared__ float sPf[SEGS][64], sQf[SEGS][64], sPb[SEGS][64], sQb[SEGS][64];
    sPf[seg][jl] = Pf; sQf[seg][jl] = Qf;
    sPb[seg][jl] = Pb; sQb[seg][jl] = Qb;
    __syncthreads();
    if (seg == 0) {
        float P = sPf[0][jl], Q = sQf[0][jl];
        for (int s2 = 1; s2 < SEGS; ++s2) {
            float Pc = sPf[s2][jl], Qc = sQf[s2][jl];
            Q = Q * Pc + Qc; P = P * Pc;
            sPf[s2][jl] = P; sQf[s2][jl] = Q;
        }
    } else if (seg == 1) {
        float P = sPb[SEGS - 1][jl], Q = sQb[SEGS - 1][jl];
        for (int s2 = SEGS - 2; s2 >= 0; --s2) {
            float Pc = sPb[s2][jl], Qc = sQb[s2][jl];
            Q = Q * Pc + Qc; P = P * Pc;
            sPb[s2][jl] = P; sQb[s2][jl] = Q;
        }
    }
    __syncthreads();
    float z = (seg > 0) ? sQf[seg - 1][jl] : 0.f;
    float s = (seg < SEGS - 1) ? sQb[seg + 1][jl] : 0.f;
    float zarr[SR];
    #pragma unroll
    for (int r = 0; r < SR; ++r) { z = z * dr[r] + 1.f; zarr[r] = z; }
    #pragma unroll
    for (int r = SR - 1; r >= 0; --r) {
        s = s * dr[r + 1] + 1.f;
        op[r * W] = zarr[r] + s - 1.f;
    }
}

// ---------------- setup: rDg = 1 / (dcol + rowD - 1), rowD via in-register row scan ----------------
__global__ __launch_bounds__(256) void k_drow(const float* __restrict__ dmat,
                                              const float* __restrict__ dcol,
                                              float* __restrict__ rDg) {
    int wid = (blockIdx.x * 256 + threadIdx.x) >> 6;  // B*H = 768 waves
    int lane = threadIdx.x & 63;
    int i = wid % H, b = wid / H;
    int base = (b * H + i) * W;
    int s0 = 3 * lane;
    float d0 = dmat[base + s0], d1 = dmat[base + s0 + 1], d2 = dmat[base + s0 + 2];
    float d3 = (lane < 63) ? dmat[base + s0 + 3] : 0.f;

    float P = d0 * d1 * d2;
    float Q = d1 * d2 + d2 + 1.f;
    #pragma unroll
    for (int off = 1; off < 64; off <<= 1) {
        float Pp = __shfl_up(P, off);
        float Qp = __shfl_up(Q, off);
        if (lane >= off) { Q = Qp * P + Q; P = Pp * P; }
    }
    float zin = __shfl_up(Q, 1);
    if (lane == 0) zin = 0.f;
    float zA = zin * d0 + 1.f;
    float zB = zA * d1 + 1.f;
    float zC = zB * d2 + 1.f;

    float Pb = d3 * d2 * d1;
    float Qb = d2 * d1 + d1 + 1.f;
    #pragma unroll
    for (int off = 1; off < 64; off <<= 1) {
        float Pp = __shfl_down(Pb, off);
        float Qp = __shfl_down(Qb, off);
        if (lane < 64 - off) { Qb = Qp * Pb + Qb; Pb = Pp * Pb; }
    }
    float sin_ = __shfl_down(Qb, 1);
    if (lane == 63) sin_ = 0.f;
    float sC = sin_ * d3 + 1.f;
    float sB = sC * d2 + 1.f;
    float sA = sB * d1 + 1.f;

    rDg[base + s0]     = 1.f / (dcol[base + s0]     + zA + sA - 2.f);
    rDg[base + s0 + 1] = 1.f / (dcol[base + s0 + 1] + zB + sB - 2.f);
    rDg[base + s0 + 2] = 1.f / (dcol[base + s0 + 2] + zC + sC - 2.f);
}

// segment-compose: inclusive prefix (fwd, threads 0..CH-1) / inclusive suffix (bwd, CH..2CH-1)
__device__ __forceinline__ void compose_scr(float2* sF, float2* sB, int t) {
    if (t < CH) {
        float P = sF[t].x, Q = sF[t].y;
        #pragma unroll
        for (int s = 1; s < SEGS; ++s) {
            float2 v = sF[s * CH + t];
            Q = Q * v.x + v.y;
            P = P * v.x;
            sF[s * CH + t] = make_float2(P, Q);
        }
    } else if (t < 2 * CH) {
        const int x = t - CH;
        float P = sB[(SEGS - 1) * CH + x].x, Q = sB[(SEGS - 1) * CH + x].y;
        #pragma unroll
        for (int s = SEGS - 2; s >= 0; --s) {
            float2 v = sB[s * CH + x];
            Q = Q * v.x + v.y;
            P = P * v.x;
            sB[s * CH + x] = make_float2(P, Q);
        }
    }
}

// ---------------- fused: 3 iterations for one (b,c) plane, entirely in LDS ----------------
__global__ __launch_bounds__(NT, 3) void k_fused(const float* __restrict__ mask,
                                                 const float* __restrict__ dmatg,
                                                 const float* __restrict__ dmatTg,
                                                 const float* __restrict__ rDg,
                                                 float* __restrict__ outg) {
    __shared__ float plane[H * PITCH];       // 148224 B
    __shared__ float2 scrF[SEGS * CH];       // 6144 B
    __shared__ float2 scrB[SEGS * CH];       // 6144 B  (total 160512 <= 163840)

    const int t = threadIdx.x;
    const int lc = t % CH;        // line index within chunk
    const int seg = t / CH;       // 0..7
    const int r0 = seg * SR;

    const int b = blockIdx.x / C;
    const int c = blockIdx.x % C;
    const float* dm  = dmatg + b * H * W;
    const float* dmT = dmatTg + b * H * W;
    const float* rDp = rDg + b * H * W;

    float cs[2 * SR];             // col-scan result at (i=r0+r, j=chunk*CH+lc)

    // ===== load f = mask plane into LDS =====
    const float* fin = mask + (size_t)(b * C + c) * H * W;
    #pragma unroll
    for (int k = 0; k < (H * W / 4) / NT; ++k) {     // 12
        int e4 = t + k * NT;
        float4 v = ((const float4*)fin)[e4];
        int i = e4 / 48;
        int j4 = (e4 % 48) * 4;
        plane[i * PITCH + j4 + 0] = v.x;
        plane[i * PITCH + j4 + 1] = v.y;
        plane[i * PITCH + j4 + 2] = v.z;
        plane[i * PITCH + j4 + 3] = v.w;
    }
    __syncthreads();

    // ===== 3 iterations =====
    for (int it = 0; it < 3; ++it) {
        // ---- col scans: cs = Zc + Sc - f (reads plane; results stay in regs) ----
        #pragma unroll
        for (int chunk = 0; chunk < 2; ++chunk) {
            const int j = chunk * CH + lc;
            float dr[SR + 1], fr[SR];
            #pragma unroll
            for (int r = 0; r < SR; ++r) {
                dr[r] = dm[(r0 + r) * W + j];
                fr[r] = plane[(r0 + r) * PITCH + j];
            }
            dr[SR] = (seg < SEGS - 1) ? dm[(r0 + SR) * W + j] : 0.f;
            float Pf = 1.f, Qf = 0.f, Pb = 1.f, Qb = 0.f;
            #pragma unroll
            for (int r = 0; r < SR; ++r) { Qf = Qf * dr[r] + fr[r]; Pf *= dr[r]; }
            #pragma unroll
            for (int r = SR - 1; r >= 0; --r) { Qb = Qb * dr[r + 1] + fr[r]; Pb *= dr[r + 1]; }
            scrF[seg * CH + lc] = make_float2(Pf, Qf);
            scrB[seg * CH + lc] = make_float2(Pb, Qb);
            __syncthreads();
            compose_scr(scrF, scrB, t);
            __syncthreads();
            float z = (seg > 0) ? scrF[(seg - 1) * CH + lc].y : 0.f;
            float s = (seg < SEGS - 1) ? scrB[(seg + 1) * CH + lc].y : 0.f;
            #pragma unroll
            for (int r = 0; r < SR; ++r) { z = z * dr[r] + fr[r]; cs[chunk * SR + r] = z; }
            #pragma unroll
            for (int r = SR - 1; r >= 0; --r) {
                s = s * dr[r + 1] + fr[r];
                cs[chunk * SR + r] += s - fr[r];
            }
            __syncthreads();
        }
        // ---- row scans: plane <- rowpart = Zr + Sr - 2f (row ownership) ----
        #pragma unroll
        for (int chunk = 0; chunk < 2; ++chunk) {
            const int i = chunk * CH + lc;
            float dr[SR + 1], fr[SR];
            #pragma unroll
            for (int r = 0; r < SR; ++r) {
                dr[r] = dmT[(r0 + r) * H + i];
                fr[r] = plane[i * PITCH + r0 + r];
            }
            dr[SR] = (seg < SEGS - 1) ? dmT[(r0 + SR) * H + i] : 0.f;
            float Pf = 1.f, Qf = 0.f, Pb = 1.f, Qb = 0.f;
            #pragma unroll
            for (int r = 0; r < SR; ++r) { Qf = Qf * dr[r] + fr[r]; Pf *= dr[r]; }
            #pragma unroll
            for (int r = SR - 1; r >= 0; --r) { Qb = Qb * dr[r + 1] + fr[r]; Pb *= dr[r + 1]; }
            scrF[seg * CH + lc] = make_float2(Pf, Qf);
            scrB[seg * CH + lc] = make_float2(Pb, Qb);
            __syncthreads();
            compose_scr(scrF, scrB, t);
            __syncthreads();
            float z = (seg > 0) ? scrF[(seg - 1) * CH + lc].y : 0.f;
            float s = (seg < SEGS - 1) ? scrB[(seg + 1) * CH + lc].y : 0.f;
            float zarr[SR];
            #pragma unroll
            for (int r = 0; r < SR; ++r) { z = z * dr[r] + fr[r]; zarr[r] = z; }
            #pragma unroll
            for (int r = SR - 1; r >= 0; --r) {
                s = s * dr[r + 1] + fr[r];
                plane[i * PITCH + r0 + r] = zarr[r] + s - 2.f * fr[r];
            }
            __syncthreads();
        }
        // ---- combine (col ownership): plane = (cs + plane) * rD ----
        #pragma unroll
        for (int chunk = 0; chunk < 2; ++chunk) {
            const int j = chunk * CH + lc;
            #pragma unroll
            for (int r = 0; r < SR; ++r) {
                const int a = (r0 + r) * PITCH + j;
                plane[a] = (cs[chunk * SR + r] + plane[a]) * rDp[(r0 + r) * W + j];
            }
        }
        __syncthreads();
    }

    // ===== store final plane =====
    float* oplane = outg + (size_t)(b * C + c) * H * W;
    #pragma unroll
    for (int k = 0; k < (H * W / 4) / NT; ++k) {
        int e4 = t + k * NT;
        int i = e4 / 48;
        int j4 = (e4 % 48) * 4;
        float4 v;
        v.x = plane[i * PITCH + j4 + 0];
        v.y = plane[i * PITCH + j4 + 1];
        v.z = plane[i * PITCH + j4 + 2];
        v.w = plane[i * PITCH + j4 + 3];
        ((float4*)oplane)[e4] = v;
    }
}

extern "C" void kernel_launch(void* const* d_in, const int* in_sizes, int n_in,
                              void* d_out, int out_size, void* d_ws, size_t ws_size,
                              hipStream_t stream) {
    const float* mask = (const float*)d_in[0];
    const float* edge = (const float*)d_in[1];
    float* out = (float*)d_out;

    float* dmat  = (float*)d_ws;            // [B,H,W]
    float* dmatT = dmat + B * H * W;        // [B,W,H]
    float* dcol  = dmatT + B * H * W;       // [B,H,W]
    float* rDg   = dcol + B * H * W;        // [B,H,W]

    k_prep<<<B * 36, 256, 0, stream>>>(edge, dmat, dmatT);
    k_dcol<<<B * 3, 512, 0, stream>>>(dmat, dcol);
    k_drow<<<(B * H) / 4, 256, 0, stream>>>(dmat, dcol, rDg);
    k_fused<<<B * C, NT, 0, stream>>>(mask, dmat, dmatT, rDg, out);
}

// Round 6
// 97.987 us; speedup vs baseline: 4.0341x; 3.4818x over previous
//
#include <hip/hip_runtime.h>

#define B 4
#define C 19
#define H 192
#define W 192
#define HW (H * W)
// 40 / ln(2): exp(-40*x) == exp2(-THETA_LOG2E*x)
#define THETA_LOG2E 57.70780163555855f

#define NT 768      // 12 waves; 1 block/CU (LDS-bound)
#define SEGS 12     // one wave per segment
#define SR 16       // rows per segment
#define PITCH 194   // even: float2 row ops; lane-stride 194 = 2-way bank conflict (free)

// ---------------- setup: dmat = exp2(-theta*relu(edge)), plus transposed copy ----------------
__global__ __launch_bounds__(256) void k_prep(const float* __restrict__ edge,
                                              float* __restrict__ dmat,
                                              float* __restrict__ dmatT) {
    __shared__ float tile[32][33];
    int blk = blockIdx.x;                 // b*36 + ty*6 + tx
    int tx = blk % 6, ty = (blk / 6) % 6, b = blk / 36;
    int lx = threadIdx.x % 32, ly = threadIdx.x / 32;    // 32 x 8
    #pragma unroll
    for (int k = 0; k < 4; ++k) {
        int il = ly + k * 8;
        int I = ty * 32 + il, J = tx * 32 + lx;
        float e = edge[(b * H + I) * W + J];
        float d = exp2f(-THETA_LOG2E * fmaxf(e, 0.f));
        dmat[(b * H + I) * W + J] = d;
        tile[il][lx] = d;
    }
    __syncthreads();
    #pragma unroll
    for (int k = 0; k < 4; ++k) {
        int jl = ly + k * 8;
        dmatT[(b * W + tx * 32 + jl) * H + ty * 32 + lx] = tile[lx][jl];
    }
}

// ---------------- setup: dcol[b,i,j] = Zc + Sc - 1 (unit-f column scan) ----------------
__global__ __launch_bounds__(512) void k_dcol(const float* __restrict__ dmat,
                                              float* __restrict__ dcol) {
    const int DS = 8, DR = 24;            // 8 segments x 24 rows, 512 threads
    int blk = blockIdx.x;                 // b*3 + jt
    int jt = blk % 3, b = blk / 3;
    int jl = threadIdx.x & 63;
    int seg = threadIdx.x >> 6;
    int j = jl + jt * 64;
    int i0 = seg * DR;
    const float* dp = dmat + ((size_t)b * H + i0) * W + j;
    float* op = dcol + ((size_t)b * H + i0) * W + j;

    float dr[DR + 1];
    #pragma unroll
    for (int r = 0; r < DR; ++r) dr[r] = dp[r * W];
    dr[DR] = (seg < DS - 1) ? dp[DR * W] : 0.f;
    float Pf = 1.f, Qf = 0.f, Pb = 1.f, Qb = 0.f;
    #pragma unroll
    for (int r = 0; r < DR; ++r) { Qf = Qf * dr[r] + 1.f; Pf *= dr[r]; }
    #pragma unroll
    for (int r = DR - 1; r >= 0; --r) { Qb = Qb * dr[r + 1] + 1.f; Pb *= dr[r + 1]; }

    __shared__ float sPf[DS][64], sQf[DS][64], sPb[DS][64], sQb[DS][64];
    sPf[seg][jl] = Pf; sQf[seg][jl] = Qf;
    sPb[seg][jl] = Pb; sQb[seg][jl] = Qb;
    __syncthreads();
    if (seg == 0) {
        float P = sPf[0][jl], Q = sQf[0][jl];
        for (int s2 = 1; s2 < DS; ++s2) {
            float Pc = sPf[s2][jl], Qc = sQf[s2][jl];
            Q = Q * Pc + Qc; P = P * Pc;
            sPf[s2][jl] = P; sQf[s2][jl] = Q;
        }
    } else if (seg == 1) {
        float P = sPb[DS - 1][jl], Q = sQb[DS - 1][jl];
        for (int s2 = DS - 2; s2 >= 0; --s2) {
            float Pc = sPb[s2][jl], Qc = sQb[s2][jl];
            Q = Q * Pc + Qc; P = P * Pc;
            sPb[s2][jl] = P; sQb[s2][jl] = Q;
        }
    }
    __syncthreads();
    float z = (seg > 0) ? sQf[seg - 1][jl] : 0.f;
    float s = (seg < DS - 1) ? sQb[seg + 1][jl] : 0.f;
    float zarr[DR];
    #pragma unroll
    for (int r = 0; r < DR; ++r) { z = z * dr[r] + 1.f; zarr[r] = z; }
    #pragma unroll
    for (int r = DR - 1; r >= 0; --r) {
        s = s * dr[r + 1] + 1.f;
        op[r * W] = zarr[r] + s - 1.f;
    }
}

// ---------------- setup: rDg = 1 / (dcol + rowD - 1), rowD via in-register row scan ----------------
__global__ __launch_bounds__(256) void k_drow(const float* __restrict__ dmat,
                                              const float* __restrict__ dcol,
                                              float* __restrict__ rDg) {
    int wid = (blockIdx.x * 256 + threadIdx.x) >> 6;  // B*H = 768 waves
    int lane = threadIdx.x & 63;
    int i = wid % H, b = wid / H;
    int base = (b * H + i) * W;
    int s0 = 3 * lane;
    float d0 = dmat[base + s0], d1 = dmat[base + s0 + 1], d2 = dmat[base + s0 + 2];
    float d3 = (lane < 63) ? dmat[base + s0 + 3] : 0.f;

    float P = d0 * d1 * d2;
    float Q = d1 * d2 + d2 + 1.f;
    #pragma unroll
    for (int off = 1; off < 64; off <<= 1) {
        float Pp = __shfl_up(P, off);
        float Qp = __shfl_up(Q, off);
        if (lane >= off) { Q = Qp * P + Q; P = Pp * P; }
    }
    float zin = __shfl_up(Q, 1);
    if (lane == 0) zin = 0.f;
    float zA = zin * d0 + 1.f;
    float zB = zA * d1 + 1.f;
    float zC = zB * d2 + 1.f;

    float Pb = d3 * d2 * d1;
    float Qb = d2 * d1 + d1 + 1.f;
    #pragma unroll
    for (int off = 1; off < 64; off <<= 1) {
        float Pp = __shfl_down(Pb, off);
        float Qp = __shfl_down(Qb, off);
        if (lane < 64 - off) { Qb = Qp * Pb + Qb; Pb = Pp * Pb; }
    }
    float sin_ = __shfl_down(Qb, 1);
    if (lane == 63) sin_ = 0.f;
    float sC = sin_ * d3 + 1.f;
    float sB = sC * d2 + 1.f;
    float sA = sB * d1 + 1.f;

    rDg[base + s0]     = 1.f / (dcol[base + s0]     + zA + sA - 2.f);
    rDg[base + s0 + 1] = 1.f / (dcol[base + s0 + 1] + zB + sB - 2.f);
    rDg[base + s0 + 2] = 1.f / (dcol[base + s0 + 2] + zC + sC - 2.f);
}

// inclusive prefix (wave 0) / suffix (wave 1) compose of the 12 per-segment affine transforms
__device__ __forceinline__ void compose12(float2* scrF, float2* scrB, int t) {
    if (t < 64) {
        float2 a = scrF[t];
        float P = a.x, Q = a.y;
        #pragma unroll
        for (int s = 1; s < SEGS; ++s) {
            float2 v = scrF[s * 64 + t];
            Q = Q * v.x + v.y;
            P = P * v.x;
            scrF[s * 64 + t] = make_float2(P, Q);
        }
    } else if (t < 128) {
        int x = t - 64;
        float2 a = scrB[(SEGS - 1) * 64 + x];
        float P = a.x, Q = a.y;
        #pragma unroll
        for (int s = SEGS - 2; s >= 0; --s) {
            float2 v = scrB[s * 64 + x];
            Q = Q * v.x + v.y;
            P = P * v.x;
            scrB[s * 64 + x] = make_float2(P, Q);
        }
    }
}

// ---- one column-chunk (64 cols): colsum = Zc + Sc - f -> cout (global, coalesced) ----
// FOLDED: f = (plane + cin) * rD  (combine of previous iteration folded into the load)
template<bool FOLDED>
__device__ __forceinline__ void col_chunk(const float* plane, float2* scrF, float2* scrB,
                                          const float* dm, const float* cin,
                                          const float* rDp, float* cout,
                                          int lane, int seg, int chunk, int t) {
    const int r0 = seg * SR;
    const int j = chunk * 64 + lane;
    float dr[SR + 1], fr[SR];
    #pragma unroll
    for (int r = 0; r < SR; ++r) dr[r] = dm[(r0 + r) * W + j];
    dr[SR] = (seg < SEGS - 1) ? dm[(r0 + SR) * W + j] : 0.f;
    #pragma unroll
    for (int r = 0; r < SR; ++r) {
        float v = plane[(r0 + r) * PITCH + j];
        if (FOLDED) v = (v + cin[(r0 + r) * W + j]) * rDp[(r0 + r) * W + j];
        fr[r] = v;
    }
    float Pf = 1.f, Qf = 0.f, Pb = 1.f, Qb = 0.f;
    #pragma unroll
    for (int r = 0; r < SR; ++r) { Qf = Qf * dr[r] + fr[r]; Pf *= dr[r]; }
    #pragma unroll
    for (int r = SR - 1; r >= 0; --r) { Qb = Qb * dr[r + 1] + fr[r]; Pb *= dr[r + 1]; }
    scrF[seg * 64 + lane] = make_float2(Pf, Qf);
    scrB[seg * 64 + lane] = make_float2(Pb, Qb);
    __syncthreads();
    compose12(scrF, scrB, t);
    __syncthreads();
    float z = (seg > 0) ? scrF[(seg - 1) * 64 + lane].y : 0.f;
    float s = (seg < SEGS - 1) ? scrB[(seg + 1) * 64 + lane].y : 0.f;
    __syncthreads();                      // scr consumed; next chunk may overwrite
    float zarr[SR];
    #pragma unroll
    for (int r = 0; r < SR; ++r) { z = z * dr[r] + fr[r]; zarr[r] = z; }
    #pragma unroll
    for (int r = SR - 1; r >= 0; --r) {
        s = s * dr[r + 1] + fr[r];
        cout[(r0 + r) * W + j] = zarr[r] + s - fr[r];
    }
}

// ---- one row-chunk (64 rows): rowpart = Zr + Sr - 2f -> plane, or final out ----
// FOLDED: f = (plane + cin) * rD ; FINAL: out = (rowpart + cfin) * rD written to outp
template<bool FOLDED, bool FINAL>
__device__ __forceinline__ void row_chunk(float* plane, float2* scrF, float2* scrB,
                                          const float* dmT, const float* cin,
                                          const float* rDp, const float* cfin,
                                          float* outp, int lane, int seg, int chunk, int t) {
    const int r0 = seg * SR;
    const int i = chunk * 64 + lane;
    float dr[SR + 1], fr[SR];
    #pragma unroll
    for (int r = 0; r < SR; ++r) dr[r] = dmT[(r0 + r) * H + i];   // coalesced across lanes
    dr[SR] = (seg < SEGS - 1) ? dmT[(r0 + SR) * H + i] : 0.f;
    #pragma unroll
    for (int q = 0; q < SR / 2; ++q) {
        float2 p2 = *(const float2*)&plane[i * PITCH + r0 + 2 * q];
        fr[2 * q] = p2.x; fr[2 * q + 1] = p2.y;
    }
    if (FOLDED) {
        #pragma unroll
        for (int q = 0; q < SR / 2; ++q) {
            float2 c2 = *(const float2*)&cin[i * W + r0 + 2 * q];
            float2 d2 = *(const float2*)&rDp[i * W + r0 + 2 * q];
            fr[2 * q]     = (fr[2 * q]     + c2.x) * d2.x;
            fr[2 * q + 1] = (fr[2 * q + 1] + c2.y) * d2.y;
        }
    }
    float Pf = 1.f, Qf = 0.f, Pb = 1.f, Qb = 0.f;
    #pragma unroll
    for (int r = 0; r < SR; ++r) { Qf = Qf * dr[r] + fr[r]; Pf *= dr[r]; }
    #pragma unroll
    for (int r = SR - 1; r >= 0; --r) { Qb = Qb * dr[r + 1] + fr[r]; Pb *= dr[r + 1]; }
    scrF[seg * 64 + lane] = make_float2(Pf, Qf);
    scrB[seg * 64 + lane] = make_float2(Pb, Qb);
    __syncthreads();
    compose12(scrF, scrB, t);
    __syncthreads();
    float z = (seg > 0) ? scrF[(seg - 1) * 64 + lane].y : 0.f;
    float s = (seg < SEGS - 1) ? scrB[(seg + 1) * 64 + lane].y : 0.f;
    __syncthreads();
    float res[SR];
    #pragma unroll
    for (int r = 0; r < SR; ++r) { z = z * dr[r] + fr[r]; res[r] = z; }
    #pragma unroll
    for (int r = SR - 1; r >= 0; --r) {
        s = s * dr[r + 1] + fr[r];
        res[r] += s - 2.f * fr[r];
    }
    if (FINAL) {
        #pragma unroll
        for (int q = 0; q < SR / 2; ++q) {
            float2 c2 = *(const float2*)&cfin[i * W + r0 + 2 * q];
            float2 d2 = *(const float2*)&rDp[i * W + r0 + 2 * q];
            float2 o;
            o.x = (res[2 * q]     + c2.x) * d2.x;
            o.y = (res[2 * q + 1] + c2.y) * d2.y;
            *(float2*)&outp[i * W + r0 + 2 * q] = o;
        }
    } else {
        #pragma unroll
        for (int q = 0; q < SR / 2; ++q) {
            *(float2*)&plane[i * PITCH + r0 + 2 * q] = make_float2(res[2 * q], res[2 * q + 1]);
        }
    }
}

// ---------------- fused: 3 iterations for one (b,c) plane ----------------
__global__ __launch_bounds__(NT) void k_fused(const float* __restrict__ mask,
                                              const float* __restrict__ dmatg,
                                              const float* __restrict__ dmatTg,
                                              const float* __restrict__ rDg,
                                              float* __restrict__ csumA,
                                              float* __restrict__ outg) {
    __shared__ float plane[H * PITCH];       // 148992 B
    __shared__ float2 scrF[SEGS * 64];       // 6144 B
    __shared__ float2 scrB[SEGS * 64];       // 6144 B   (total 161280 <= 163840)

    const int t = threadIdx.x, lane = t & 63, seg = t >> 6;
    const int bc = blockIdx.x;
    const int b = bc / C;
    const float* dm  = dmatg + b * HW;
    const float* dmT = dmatTg + b * HW;
    const float* rDp = rDg + b * HW;
    float* csA = csumA + (size_t)bc * HW;    // ws scratch slice
    float* csB = outg + (size_t)bc * HW;     // d_out doubles as ping-pong scratch
    const float* fin = mask + (size_t)bc * HW;

    // load mask -> plane
    #pragma unroll
    for (int k = 0; k < (HW / 4) / NT; ++k) {    // 12
        int e4 = t + k * NT;
        float4 v = ((const float4*)fin)[e4];
        int i = e4 / (W / 4), j4 = (e4 % (W / 4)) * 4;
        float* p = &plane[i * PITCH + j4];
        *(float2*)p       = make_float2(v.x, v.y);
        *(float2*)(p + 2) = make_float2(v.z, v.w);
    }
    __syncthreads();

    // iter 0: f0 = plane(mask); csum0 -> csA; plane <- rowpart0
    for (int ch = 0; ch < 3; ++ch)
        col_chunk<false>(plane, scrF, scrB, dm, nullptr, nullptr, csA, lane, seg, ch, t);
    __syncthreads();
    for (int ch = 0; ch < 3; ++ch)
        row_chunk<false, false>(plane, scrF, scrB, dmT, nullptr, nullptr, nullptr, nullptr, lane, seg, ch, t);
    __syncthreads();
    // iter 1: f1 = (plane + csA)*rD; csum1 -> csB; plane <- rowpart1
    for (int ch = 0; ch < 3; ++ch)
        col_chunk<true>(plane, scrF, scrB, dm, csA, rDp, csB, lane, seg, ch, t);
    __syncthreads();
    for (int ch = 0; ch < 3; ++ch)
        row_chunk<true, false>(plane, scrF, scrB, dmT, csA, rDp, nullptr, nullptr, lane, seg, ch, t);
    __syncthreads();
    // iter 2: f2 = (plane + csB)*rD; csum2 -> csA; out = (rowpart2 + csA)*rD
    for (int ch = 0; ch < 3; ++ch)
        col_chunk<true>(plane, scrF, scrB, dm, csB, rDp, csA, lane, seg, ch, t);
    __syncthreads();
    for (int ch = 0; ch < 3; ++ch)
        row_chunk<true, true>(plane, scrF, scrB, dmT, csB, rDp, csA, csB, lane, seg, ch, t);
}

extern "C" void kernel_launch(void* const* d_in, const int* in_sizes, int n_in,
                              void* d_out, int out_size, void* d_ws, size_t ws_size,
                              hipStream_t stream) {
    const float* mask = (const float*)d_in[0];
    const float* edge = (const float*)d_in[1];
    float* out = (float*)d_out;

    float* dmat  = (float*)d_ws;            // [B,H,W]
    float* dmatT = dmat + B * HW;           // [B,W,H]
    float* dcol  = dmatT + B * HW;          // [B,H,W]
    float* rDg   = dcol + B * HW;           // [B,H,W]
    float* csumA = rDg + B * HW;            // [B*C,H,W]

    k_prep<<<B * 36, 256, 0, stream>>>(edge, dmat, dmatT);
    k_dcol<<<B * 3, 512, 0, stream>>>(dmat, dcol);
    k_drow<<<(B * H) / 4, 256, 0, stream>>>(dmat, dcol, rDg);
    k_fused<<<B * C, NT, 0, stream>>>(mask, dmat, dmatT, rDg, csumA, out);
}